// Round 8
// baseline (80.001 us; speedup 1.0000x reference)
//
#include <hip/hip_runtime.h>
#include <math.h>

typedef unsigned long long u64;

#define S_DIM 1023
#define B_DIM 64
#define I_DIM 1024
#define CTX_DIM 784
#define CTX4 196          // CTX_DIM / 4
#define NWROWS 16         // 2^M buckets
#define NTASK (S_DIM * NWROWS)
#define ROW_BLOCKS 1024
#define NWAVES (ROW_BLOCKS * 4)

#define LR_C 0.01f
#define WC_C 5.0f
#define LO_C (-6.906754778648554f)
#define HI_C ( 6.906754778648554f)

__device__ __forceinline__ float dot4(float4 a, float4 b) {
    return a.x * b.x + a.y * b.y + a.z * b.z + a.w * b.w;
}

__device__ __forceinline__ float4 upd4(float4 w, float4 a, float c) {
    float4 r;
    r.x = fminf(fmaxf(w.x - c * a.x, -WC_C), WC_C);
    r.y = fminf(fmaxf(w.y - c * a.y, -WC_C), WC_C);
    r.z = fminf(fmaxf(w.z - c * a.z, -WC_C), WC_C);
    r.w = fminf(fmaxf(w.w - c * a.w, -WC_C), WC_C);
    return r;
}

// ---------------- kernel A: context -> float4-transposed layout + bias row ----------------
__global__ __launch_bounds__(256) void prep_kernel(
    const float* __restrict__ context,   // [B, CTX]
    const float* __restrict__ bias,      // [1]
    float4* __restrict__ ctxT4,          // [CTX4][B]
    float* __restrict__ out_logits)      // [B, S+1]
{
    int g = blockIdx.x * 256 + threadIdx.x;
    int k4 = g >> 6;
    int b  = g & 63;
    ctxT4[g] = *(const float4*)(context + (size_t)b * CTX_DIM + k4 * 4);
    if (g < B_DIM) out_logits[(size_t)g * (S_DIM + 1)] = bias[0];
}

// ---------------- kernel B: halfspace hash, 2 s per 512-thread block ----------------
__global__ __launch_bounds__(512) void gln_idx_kernel(
    const float* __restrict__ cm,        // [S, 4, CTX]
    const float* __restrict__ cb,        // [S, 4]
    const float4* __restrict__ ctxT4,    // [CTX4][B]
    u64* __restrict__ mask_g)            // [S*16]
{
    __shared__ float red[2][4][4][64];   // [half][q][m][b]
    __shared__ int   bits[2][4][64];
    __shared__ float cb_lds[2][4];

    const int t  = threadIdx.x;
    const int sh = t >> 8;               // which s this half handles
    const int tt = t & 255;
    const int s  = blockIdx.x * 2 + sh;
    const int se = (s < S_DIM) ? s : (S_DIM - 1);   // clamp for safe loads

    if (tt < 4) cb_lds[sh][tt] = cb[se * 4 + tt];

    const int b = tt & 63;
    const int q = __builtin_amdgcn_readfirstlane(tt >> 6);  // k-quarter, uniform
    const float4* cmr = (const float4*)(cm + (size_t)se * 4 * CTX_DIM);

    float a0 = 0.f, a1 = 0.f, a2 = 0.f, a3 = 0.f;
    const int k0 = q * 49;
    #pragma unroll 7
    for (int kk = 0; kk < 49; ++kk) {
        int k4 = k0 + kk;
        float4 c4 = ctxT4[k4 * 64 + b];          // coalesced; L1-shared between halves
        a0 += dot4(cmr[k4], c4);                 // uniform -> scalar/broadcast load
        a1 += dot4(cmr[CTX4 + k4], c4);
        a2 += dot4(cmr[2 * CTX4 + k4], c4);
        a3 += dot4(cmr[3 * CTX4 + k4], c4);
    }
    red[sh][q][0][b] = a0;
    red[sh][q][1][b] = a1;
    red[sh][q][2][b] = a2;
    red[sh][q][3][b] = a3;
    __syncthreads();

    {
        int m = tt >> 6, bb = tt & 63;
        float sum = red[sh][0][m][bb] + red[sh][1][m][bb]
                  + red[sh][2][m][bb] + red[sh][3][m][bb];
        bits[sh][m][bb] = (sum > cb_lds[sh][m]) ? 1 : 0;
    }
    __syncthreads();

    if (tt < B_DIM) {    // one full wave per half
        int v = bits[sh][0][tt] + 2 * bits[sh][1][tt]
              + 4 * bits[sh][2][tt] + 8 * bits[sh][3][tt];
        u64 my = 0;
        #pragma unroll
        for (int kk = 0; kk < NWROWS; ++kk) {
            u64 mk = __ballot(v == kk);
            if (tt == kk) my = mk;
        }
        if (tt < NWROWS && s < S_DIM) mask_g[s * NWROWS + tt] = my;
    }
}

// ---------------- kernel C: persistent waves, 1 row/task, batch-4 members ----------------
__device__ __forceinline__ void process_task(
    int task, int ln,
    const float* __restrict__ logit, const float* __restrict__ target,
    const float* __restrict__ weights, const u64* __restrict__ mask_g,
    float* __restrict__ out_logits, float* __restrict__ new_weights)
{
    const float4* wr = (const float4*)weights + (size_t)task * 256;
    float4 w0 = wr[ln], w1 = wr[ln + 64], w2 = wr[ln + 128], w3 = wr[ln + 192];
    u64 m = mask_g[task];
    float4* dst = (float4*)new_weights + (size_t)task * 256;

    if (!m) {                            // untouched row: verbatim copy
        dst[ln]       = w0;
        dst[ln + 64]  = w1;
        dst[ln + 128] = w2;
        dst[ln + 192] = w3;
        return;
    }
    const int s = task >> 4;
    const int last = 63 - __clzll(m);

    while (m) {
        const int b0 = __builtin_ctzll(m); m &= m - 1;
        int b1 = -1, b2 = -1, b3 = -1;
        if (m) { b1 = __builtin_ctzll(m); m &= m - 1;
            if (m) { b2 = __builtin_ctzll(m); m &= m - 1;
                if (m) { b3 = __builtin_ctzll(m); m &= m - 1; } } }

        // issue ALL logit loads (up to 16 float4 = 256 B/lane in flight)
        const float4* lg0 = (const float4*)logit + (size_t)b0 * 256;
        float4 a00 = lg0[ln], a01 = lg0[ln+64], a02 = lg0[ln+128], a03 = lg0[ln+192];
        float4 a10 = a00, a11 = a01, a12 = a02, a13 = a03;
        float4 a20 = a00, a21 = a01, a22 = a02, a23 = a03;
        float4 a30 = a00, a31 = a01, a32 = a02, a33 = a03;
        if (b1 >= 0) {
            const float4* lg = (const float4*)logit + (size_t)b1 * 256;
            a10 = lg[ln]; a11 = lg[ln+64]; a12 = lg[ln+128]; a13 = lg[ln+192];
        }
        if (b2 >= 0) {
            const float4* lg = (const float4*)logit + (size_t)b2 * 256;
            a20 = lg[ln]; a21 = lg[ln+64]; a22 = lg[ln+128]; a23 = lg[ln+192];
        }
        if (b3 >= 0) {
            const float4* lg = (const float4*)logit + (size_t)b3 * 256;
            a30 = lg[ln]; a31 = lg[ln+64]; a32 = lg[ln+128]; a33 = lg[ln+192];
        }

        float p0 = dot4(a00,w0) + dot4(a01,w1) + dot4(a02,w2) + dot4(a03,w3);
        float p1 = dot4(a10,w0) + dot4(a11,w1) + dot4(a12,w2) + dot4(a13,w3);
        float p2 = dot4(a20,w0) + dot4(a21,w1) + dot4(a22,w2) + dot4(a23,w3);
        float p3 = dot4(a30,w0) + dot4(a31,w1) + dot4(a32,w2) + dot4(a33,w3);

        // 4 independent butterfly reduces, interleaved (6 levels amortized)
        #pragma unroll
        for (int off = 32; off; off >>= 1) {
            p0 += __shfl_xor(p0, off, 64);
            p1 += __shfl_xor(p1, off, 64);
            p2 += __shfl_xor(p2, off, 64);
            p3 += __shfl_xor(p3, off, 64);
        }

        {
            float o = fminf(fmaxf(p0, LO_C), HI_C);
            if (ln == 0) out_logits[(size_t)b0 * (S_DIM + 1) + s + 1] = o;
            if (b0 == last) {
                float c = LR_C * (1.0f / (1.0f + expf(-o)) - target[b0]);
                dst[ln]       = upd4(w0, a00, c);
                dst[ln + 64]  = upd4(w1, a01, c);
                dst[ln + 128] = upd4(w2, a02, c);
                dst[ln + 192] = upd4(w3, a03, c);
            }
        }
        if (b1 >= 0) {
            float o = fminf(fmaxf(p1, LO_C), HI_C);
            if (ln == 0) out_logits[(size_t)b1 * (S_DIM + 1) + s + 1] = o;
            if (b1 == last) {
                float c = LR_C * (1.0f / (1.0f + expf(-o)) - target[b1]);
                dst[ln]       = upd4(w0, a10, c);
                dst[ln + 64]  = upd4(w1, a11, c);
                dst[ln + 128] = upd4(w2, a12, c);
                dst[ln + 192] = upd4(w3, a13, c);
            }
        }
        if (b2 >= 0) {
            float o = fminf(fmaxf(p2, LO_C), HI_C);
            if (ln == 0) out_logits[(size_t)b2 * (S_DIM + 1) + s + 1] = o;
            if (b2 == last) {
                float c = LR_C * (1.0f / (1.0f + expf(-o)) - target[b2]);
                dst[ln]       = upd4(w0, a20, c);
                dst[ln + 64]  = upd4(w1, a21, c);
                dst[ln + 128] = upd4(w2, a22, c);
                dst[ln + 192] = upd4(w3, a23, c);
            }
        }
        if (b3 >= 0) {
            float o = fminf(fmaxf(p3, LO_C), HI_C);
            if (ln == 0) out_logits[(size_t)b3 * (S_DIM + 1) + s + 1] = o;
            if (b3 == last) {
                float c = LR_C * (1.0f / (1.0f + expf(-o)) - target[b3]);
                dst[ln]       = upd4(w0, a30, c);
                dst[ln + 64]  = upd4(w1, a31, c);
                dst[ln + 128] = upd4(w2, a32, c);
                dst[ln + 192] = upd4(w3, a33, c);
            }
        }
    }
}

__global__ __launch_bounds__(256, 4) void gln_row4_kernel(
    const float* __restrict__ logit,     // [B, I]
    const float* __restrict__ target,    // [B]
    const float* __restrict__ weights,   // [S, 16, I]
    const u64*   __restrict__ mask_g,    // [S*16]
    float* __restrict__ out_logits,      // [B, S+1]
    float* __restrict__ new_weights)     // [S, 16, I]
{
    const int wid = blockIdx.x * 4 + (threadIdx.x >> 6);
    const int ln  = threadIdx.x & 63;
    for (int task = wid; task < NTASK; task += NWAVES)
        process_task(task, ln, logit, target, weights, mask_g, out_logits, new_weights);
}

extern "C" void kernel_launch(void* const* d_in, const int* in_sizes, int n_in,
                              void* d_out, int out_size, void* d_ws, size_t ws_size,
                              hipStream_t stream) {
    const float* logit   = (const float*)d_in[0];   // [B, I, 1]
    const float* context = (const float*)d_in[1];   // [B, CTX]
    const float* target  = (const float*)d_in[2];   // [B, 1]
    const float* cm      = (const float*)d_in[3];   // [1, S, 4, CTX]
    const float* cb      = (const float*)d_in[4];   // [1, S, 4, 1]
    const float* weights = (const float*)d_in[5];   // [1, S, 16, I]
    const float* bias    = (const float*)d_in[6];   // [1]

    float* out_logits  = (float*)d_out;                       // [B, S+1]
    float* new_weights = out_logits + (size_t)B_DIM * (S_DIM + 1);

    char* ws = (char*)d_ws;
    float4* ctxT4 = (float4*)ws;                 ws += (size_t)CTX4 * B_DIM * 16;
    u64*    mask_g  = (u64*)ws;

    prep_kernel<<<CTX4 * B_DIM / 256, 256, 0, stream>>>(context, bias, ctxT4, out_logits);
    gln_idx_kernel<<<(S_DIM + 1) / 2, 512, 0, stream>>>(cm, cb, ctxT4, mask_g);
    gln_row4_kernel<<<ROW_BLOCKS, 256, 0, stream>>>(logit, target, weights, mask_g,
                                                    out_logits, new_weights);
}

// Round 9
// 62.483 us; speedup vs baseline: 1.2804x; 1.2804x over previous
//
#include <hip/hip_runtime.h>
#include <math.h>

typedef unsigned long long u64;

#define S_DIM 1023
#define B_DIM 64
#define I_DIM 1024
#define CTX_DIM 784
#define CTX4 196          // CTX_DIM / 4
#define NWROWS 16         // 2^M buckets
#define NTASK (S_DIM * NWROWS)

#define LR_C 0.01f
#define WC_C 5.0f
#define LO_C (-6.906754778648554f)
#define HI_C ( 6.906754778648554f)

__device__ __forceinline__ float dot4(float4 a, float4 b) {
    return a.x * b.x + a.y * b.y + a.z * b.z + a.w * b.w;
}

__device__ __forceinline__ float4 upd4(float4 w, float4 a, float c) {
    float4 r;
    r.x = fminf(fmaxf(w.x - c * a.x, -WC_C), WC_C);
    r.y = fminf(fmaxf(w.y - c * a.y, -WC_C), WC_C);
    r.z = fminf(fmaxf(w.z - c * a.z, -WC_C), WC_C);
    r.w = fminf(fmaxf(w.w - c * a.w, -WC_C), WC_C);
    return r;
}

// ---------------- kernel A: context -> float4-transposed layout + bias row ----------------
__global__ __launch_bounds__(256) void prep_kernel(
    const float* __restrict__ context,   // [B, CTX]
    const float* __restrict__ bias,      // [1]
    float4* __restrict__ ctxT4,          // [CTX4][B]
    float* __restrict__ out_logits)      // [B, S+1]
{
    int g = blockIdx.x * 256 + threadIdx.x;
    int k4 = g >> 6;
    int b  = g & 63;
    ctxT4[g] = *(const float4*)(context + (size_t)b * CTX_DIM + k4 * 4);
    if (g < B_DIM) out_logits[(size_t)g * (S_DIM + 1)] = bias[0];
}

// ---------------- kernel B: halfspace hash -> membership masks (R7 version) ----------------
__global__ __launch_bounds__(256) void gln_idx_kernel(
    const float* __restrict__ cm,        // [S, 4, CTX]
    const float* __restrict__ cb,        // [S, 4]
    const float4* __restrict__ ctxT4,    // [CTX4][B]
    u64* __restrict__ mask_g)            // [S*16]
{
    __shared__ float red[4][4][64];      // [q][m][b]
    __shared__ int   bits[4][64];
    __shared__ float cb_lds[4];

    const int s = blockIdx.x;
    const int t = threadIdx.x;
    if (t < 4) cb_lds[t] = cb[s * 4 + t];

    const int b = t & 63;
    const int q = __builtin_amdgcn_readfirstlane(t >> 6);   // k-quarter, uniform
    const float4* cmr = (const float4*)(cm + (size_t)s * 4 * CTX_DIM);

    float a0 = 0.f, a1 = 0.f, a2 = 0.f, a3 = 0.f;
    const int k0 = q * 49;
    #pragma unroll 7
    for (int kk = 0; kk < 49; ++kk) {
        int k4 = k0 + kk;
        float4 c4 = ctxT4[k4 * 64 + b];
        a0 += dot4(cmr[k4], c4);
        a1 += dot4(cmr[CTX4 + k4], c4);
        a2 += dot4(cmr[2 * CTX4 + k4], c4);
        a3 += dot4(cmr[3 * CTX4 + k4], c4);
    }
    red[q][0][b] = a0;
    red[q][1][b] = a1;
    red[q][2][b] = a2;
    red[q][3][b] = a3;
    __syncthreads();

    {
        int m = t >> 6, bb = t & 63;
        float sum = red[0][m][bb] + red[1][m][bb] + red[2][m][bb] + red[3][m][bb];
        bits[m][bb] = (sum > cb_lds[m]) ? 1 : 0;
    }
    __syncthreads();

    if (t < B_DIM) {
        int v = bits[0][t] + 2 * bits[1][t] + 4 * bits[2][t] + 8 * bits[3][t];
        u64 my = 0;
        #pragma unroll
        for (int kk = 0; kk < NWROWS; ++kk) {
            u64 mk = __ballot(v == kk);
            if (t == kk) my = mk;
        }
        if (t < NWROWS) mask_g[s * NWROWS + t] = my;
    }
}

// ---------------- per-task body (R7 batch-2 member loop) ----------------
__device__ __forceinline__ void process_task_pl(
    int task, int ln, u64 m,
    float4 w0, float4 w1, float4 w2, float4 w3,
    const float* __restrict__ logit, const float* __restrict__ target,
    float* __restrict__ out_logits, float* __restrict__ new_weights)
{
    float4* dst = (float4*)new_weights + (size_t)task * 256;
    if (!m) {                              // untouched row: verbatim copy
        dst[ln]       = w0;
        dst[ln + 64]  = w1;
        dst[ln + 128] = w2;
        dst[ln + 192] = w3;
        return;
    }
    const int s = task >> 4;
    const int last = 63 - __clzll(m);

    while (m) {
        const int b0 = __builtin_ctzll(m); m &= m - 1;
        int b1 = -1;
        if (m) { b1 = __builtin_ctzll(m); m &= m - 1; }

        const float4* lg0 = (const float4*)logit + (size_t)b0 * 256;
        float4 a00 = lg0[ln], a01 = lg0[ln+64], a02 = lg0[ln+128], a03 = lg0[ln+192];
        float4 a10, a11, a12, a13;
        if (b1 >= 0) {
            const float4* lg1 = (const float4*)logit + (size_t)b1 * 256;
            a10 = lg1[ln]; a11 = lg1[ln+64]; a12 = lg1[ln+128]; a13 = lg1[ln+192];
        } else {
            a10 = a00; a11 = a01; a12 = a02; a13 = a03;
        }

        float p0 = dot4(a00,w0) + dot4(a01,w1) + dot4(a02,w2) + dot4(a03,w3);
        float p1 = dot4(a10,w0) + dot4(a11,w1) + dot4(a12,w2) + dot4(a13,w3);

        #pragma unroll
        for (int off = 32; off; off >>= 1) {
            p0 += __shfl_xor(p0, off, 64);
            p1 += __shfl_xor(p1, off, 64);
        }

        {
            float o = fminf(fmaxf(p0, LO_C), HI_C);
            if (ln == 0) out_logits[(size_t)b0 * (S_DIM + 1) + s + 1] = o;
            if (b0 == last) {
                float c = LR_C * (1.0f / (1.0f + expf(-o)) - target[b0]);
                dst[ln]       = upd4(w0, a00, c);
                dst[ln + 64]  = upd4(w1, a01, c);
                dst[ln + 128] = upd4(w2, a02, c);
                dst[ln + 192] = upd4(w3, a03, c);
            }
        }
        if (b1 >= 0) {
            float o = fminf(fmaxf(p1, LO_C), HI_C);
            if (ln == 0) out_logits[(size_t)b1 * (S_DIM + 1) + s + 1] = o;
            if (b1 == last) {
                float c = LR_C * (1.0f / (1.0f + expf(-o)) - target[b1]);
                dst[ln]       = upd4(w0, a10, c);
                dst[ln + 64]  = upd4(w1, a11, c);
                dst[ln + 128] = upd4(w2, a12, c);
                dst[ln + 192] = upd4(w3, a13, c);
            }
        }
    }
}

// ---------------- kernel C: 4 tasks/wave, rotated W prefetch pipeline ----------------
// Task i+1's W row is issued BEFORE task i's member loop and stores, so
// (a) W latency hides under member processing, (b) waiting on W(i+1) never
// waits on task i's stores (they are younger in the vmcnt queue).
__global__ __launch_bounds__(256, 4) void gln_row5_kernel(
    const float* __restrict__ logit,     // [B, I]
    const float* __restrict__ target,    // [B]
    const float* __restrict__ weights,   // [S, 16, I]
    const u64*   __restrict__ mask_g,    // [S*16]
    float* __restrict__ out_logits,      // [B, S+1]
    float* __restrict__ new_weights)     // [S, 16, I]
{
    const int wv = threadIdx.x >> 6;
    const int ln = threadIdx.x & 63;
    const int base = (blockIdx.x * 4 + wv) * 4;   // 4 adjacent tasks, same s

    // all 4 masks up front (uniform, L2-hot)
    const u64 mA = mask_g[base + 0];
    const u64 mB = mask_g[base + 1];
    const u64 mC = mask_g[base + 2];
    const u64 mD = mask_g[base + 3];

    const float4* W = (const float4*)weights;
    float4 c0, c1, c2, c3, n0, n1, n2, n3;

    {   // W(task0)
        const float4* p = W + (size_t)(base + 0) * 256;
        c0 = p[ln]; c1 = p[ln + 64]; c2 = p[ln + 128]; c3 = p[ln + 192];
    }
    {   // prefetch W(task1)
        const float4* p = W + (size_t)(base + 1) * 256;
        n0 = p[ln]; n1 = p[ln + 64]; n2 = p[ln + 128]; n3 = p[ln + 192];
    }
    process_task_pl(base + 0, ln, mA, c0, c1, c2, c3, logit, target, out_logits, new_weights);

    c0 = n0; c1 = n1; c2 = n2; c3 = n3;
    {   // prefetch W(task2)
        const float4* p = W + (size_t)(base + 2) * 256;
        n0 = p[ln]; n1 = p[ln + 64]; n2 = p[ln + 128]; n3 = p[ln + 192];
    }
    process_task_pl(base + 1, ln, mB, c0, c1, c2, c3, logit, target, out_logits, new_weights);

    c0 = n0; c1 = n1; c2 = n2; c3 = n3;
    {   // prefetch W(task3)
        const float4* p = W + (size_t)(base + 3) * 256;
        n0 = p[ln]; n1 = p[ln + 64]; n2 = p[ln + 128]; n3 = p[ln + 192];
    }
    process_task_pl(base + 2, ln, mC, c0, c1, c2, c3, logit, target, out_logits, new_weights);

    process_task_pl(base + 3, ln, mD, n0, n1, n2, n3, logit, target, out_logits, new_weights);
}

extern "C" void kernel_launch(void* const* d_in, const int* in_sizes, int n_in,
                              void* d_out, int out_size, void* d_ws, size_t ws_size,
                              hipStream_t stream) {
    const float* logit   = (const float*)d_in[0];   // [B, I, 1]
    const float* context = (const float*)d_in[1];   // [B, CTX]
    const float* target  = (const float*)d_in[2];   // [B, 1]
    const float* cm      = (const float*)d_in[3];   // [1, S, 4, CTX]
    const float* cb      = (const float*)d_in[4];   // [1, S, 4, 1]
    const float* weights = (const float*)d_in[5];   // [1, S, 16, I]
    const float* bias    = (const float*)d_in[6];   // [1]

    float* out_logits  = (float*)d_out;                       // [B, S+1]
    float* new_weights = out_logits + (size_t)B_DIM * (S_DIM + 1);

    char* ws = (char*)d_ws;
    float4* ctxT4 = (float4*)ws;                 ws += (size_t)CTX4 * B_DIM * 16;
    u64*    mask_g  = (u64*)ws;

    prep_kernel<<<CTX4 * B_DIM / 256, 256, 0, stream>>>(context, bias, ctxT4, out_logits);
    gln_idx_kernel<<<S_DIM, 256, 0, stream>>>(cm, cb, ctxT4, mask_g);
    gln_row5_kernel<<<NTASK / 16, 256, 0, stream>>>(logit, target, weights, mask_g,
                                                    out_logits, new_weights);
}